// Round 3
// baseline (157.182 us; speedup 1.0000x reference)
//
#include <hip/hip_runtime.h>

// CustomLoss: fused 4-way reduction over N rows -> scalar loss.
// total = 10*mean((t-c)^2) + 0.1*mean(u-l) + 10*mean(max(l-u,0)) + 0.5*sum(dir)/N
// where c=(l+u)/2, dir = pv==0 ? relu(c-prev) : relu(prev-c).
//
// Round 3: single-pass reduction. Main loop = round-1 body (VGPR 20,
// occupancy 56% — proven; round-2 unroll-4 crossed the VGPR=64 occupancy
// cliff and regressed). Finalization fused via threadfence + ticket counter
// (rocPRIM-style): saves the second launch + its latency tail (~4-6 us).

constexpr int BLOCK = 256;
constexpr int GRID_MAX = 2048;

__device__ inline void block_reduce4(float& a, float& b, float& c, float& d) {
    #pragma unroll
    for (int off = 32; off > 0; off >>= 1) {
        a += __shfl_down(a, off);
        b += __shfl_down(b, off);
        c += __shfl_down(c, off);
        d += __shfl_down(d, off);
    }
    __shared__ float s[4][BLOCK / 64];
    const int lane = threadIdx.x & 63;
    const int wid  = threadIdx.x >> 6;
    if (lane == 0) { s[0][wid] = a; s[1][wid] = b; s[2][wid] = c; s[3][wid] = d; }
    __syncthreads();
    if (threadIdx.x == 0) {
        #pragma unroll
        for (int w = 1; w < BLOCK / 64; ++w) {
            a += s[0][w]; b += s[1][w]; c += s[2][w]; d += s[3][w];
        }
    }
}

__global__ __launch_bounds__(BLOCK) void loss_fused(
    const float4* __restrict__ pred4,   // 2 float4 per group of 4 rows
    const float4* __restrict__ tgt4,
    const float4* __restrict__ prev4,
    const int4*   __restrict__ pv4,
    const float*  __restrict__ pred,    // scalar tail
    const float*  __restrict__ tgt,
    const float*  __restrict__ prev,
    const int*    __restrict__ pv,
    float4* __restrict__ partials,
    unsigned int* __restrict__ ticket,  // zeroed per call via hipMemsetAsync
    float* __restrict__ out,
    long long n, long long nthreads, float inv_n)
{
    const long long ngroups = n >> 2;
    const long long tid = (long long)blockIdx.x * BLOCK + threadIdx.x;
    const long long stride = nthreads;

    float sc = 0.f, sw = 0.f, sv = 0.f, sd = 0.f;

    for (long long g = tid; g < ngroups; g += stride) {
        const float4 p0 = pred4[2 * g];
        const float4 p1 = pred4[2 * g + 1];
        const float4 t  = tgt4[g];
        const float4 pr = prev4[g];
        const int4   v  = pv4[g];

        const float l[4]  = { p0.x, p0.z, p1.x, p1.z };
        const float u[4]  = { p0.y, p0.w, p1.y, p1.w };
        const float tt[4] = { t.x, t.y, t.z, t.w };
        const float pp[4] = { pr.x, pr.y, pr.z, pr.w };
        const int   vv[4] = { v.x, v.y, v.z, v.w };

        #pragma unroll
        for (int j = 0; j < 4; ++j) {
            const float c = (l[j] + u[j]) * 0.5f;
            const float d = tt[j] - c;
            sc += d * d;
            sw += u[j] - l[j];
            sv += fmaxf(l[j] - u[j], 0.f);
            const float dif = (vv[j] == 0) ? (c - pp[j]) : (pp[j] - c);
            sd += fmaxf(dif, 0.f);
        }
    }
    // Scalar tail (n % 4 leftovers).
    for (long long i = (ngroups << 2) + tid; i < n; i += stride) {
        const float lo = pred[2 * i];
        const float up = pred[2 * i + 1];
        const float c  = (lo + up) * 0.5f;
        const float d  = tgt[i] - c;
        sc += d * d;
        sw += up - lo;
        sv += fmaxf(lo - up, 0.f);
        const float dif = (pv[i] == 0) ? (c - prev[i]) : (prev[i] - c);
        sd += fmaxf(dif, 0.f);
    }

    block_reduce4(sc, sw, sv, sd);

    // --- single-pass finalize: last block to arrive reduces all partials ---
    __shared__ bool amLast;
    if (threadIdx.x == 0) {
        partials[blockIdx.x] = make_float4(sc, sw, sv, sd);
        __threadfence();  // agent-scope release: partials visible device-wide
        const unsigned int old =
            __hip_atomic_fetch_add(ticket, 1u, __ATOMIC_ACQ_REL, __HIP_MEMORY_SCOPE_AGENT);
        amLast = (old == (unsigned int)gridDim.x - 1u);
    }
    __syncthreads();

    if (amLast) {
        __threadfence();  // agent-scope acquire: invalidate stale L2 lines
        float fc = 0.f, fw = 0.f, fv = 0.f, fd = 0.f;
        const int nparts = (int)gridDim.x;
        for (int i = threadIdx.x; i < nparts; i += BLOCK) {
            const float4 p = partials[i];
            fc += p.x; fw += p.y; fv += p.z; fd += p.w;
        }
        __syncthreads();  // protect block_reduce4's shared scratch (reused)
        block_reduce4(fc, fw, fv, fd);
        if (threadIdx.x == 0) {
            out[0] = 10.0f * fc * inv_n
                   + 0.1f  * fw * inv_n
                   + 10.0f * fv * inv_n
                   + 0.5f  * fd * inv_n;
        }
    }
}

extern "C" void kernel_launch(void* const* d_in, const int* in_sizes, int n_in,
                              void* d_out, int out_size, void* d_ws, size_t ws_size,
                              hipStream_t stream) {
    const float* pred = (const float*)d_in[0];   // (N,2) f32
    const float* tgt  = (const float*)d_in[1];   // (N,1) f32
    const float* prev = (const float*)d_in[2];   // (N,)  f32
    const int*   pv   = (const int*)d_in[3];     // (N,)  int (0/1)
    float*       out  = (float*)d_out;

    const long long n = (long long)in_sizes[2];  // prev_pci element count = N

    int grid = GRID_MAX;
    // workspace layout: [grid * float4 partials][4B ticket counter]
    while (grid > 1 && ws_size < (size_t)grid * sizeof(float4) + sizeof(unsigned int)) {
        grid >>= 1;
    }
    float4*       partials = (float4*)d_ws;
    unsigned int* ticket   = (unsigned int*)((char*)d_ws + (size_t)grid * sizeof(float4));

    hipMemsetAsync(ticket, 0, sizeof(unsigned int), stream);

    loss_fused<<<grid, BLOCK, 0, stream>>>(
        (const float4*)pred, (const float4*)tgt, (const float4*)prev, (const int4*)pv,
        pred, tgt, prev, pv,
        partials, ticket, out,
        n, (long long)grid * BLOCK, 1.0f / (float)n);
}

// Round 4
// 47.944 us; speedup vs baseline: 3.2784x; 3.2784x over previous
//
#include <hip/hip_runtime.h>

// CustomLoss: fused 4-way reduction over N rows -> scalar loss.
// total = 10*mean((t-c)^2) + 0.1*mean(u-l) + 10*mean(max(l-u,0)) + 0.5*sum(dir)/N
// where c=(l+u)/2, dir = pv==0 ? relu(c-prev) : relu(prev-c).
//
// Round 4: round-1 main loop (VGPR 20, occupancy 56% — proven best) +
// single-kernel finalize via one relaxed device-scope fp32 atomicAdd per
// block into d_out[0] (zeroed per call by a 4B memset node).
//
// Round-3 lesson (DO NOT reintroduce): agent-scope fences/ACQ_REL RMWs on
// gfx950 compile to full per-XCD L2 writeback+invalidate (non-coherent L2s,
// coherence point = LLC) -> 2048 block-end fences cost ~200us. Relaxed
// atomics execute AT the LLC with no cache maintenance -> cheap.

constexpr int BLOCK = 256;
constexpr int GRID_MAX = 2048;

__device__ inline void block_reduce4(float& a, float& b, float& c, float& d) {
    #pragma unroll
    for (int off = 32; off > 0; off >>= 1) {
        a += __shfl_down(a, off);
        b += __shfl_down(b, off);
        c += __shfl_down(c, off);
        d += __shfl_down(d, off);
    }
    __shared__ float s[4][BLOCK / 64];
    const int lane = threadIdx.x & 63;
    const int wid  = threadIdx.x >> 6;
    if (lane == 0) { s[0][wid] = a; s[1][wid] = b; s[2][wid] = c; s[3][wid] = d; }
    __syncthreads();
    if (threadIdx.x == 0) {
        #pragma unroll
        for (int w = 1; w < BLOCK / 64; ++w) {
            a += s[0][w]; b += s[1][w]; c += s[2][w]; d += s[3][w];
        }
    }
}

__global__ __launch_bounds__(BLOCK) void loss_fused(
    const float4* __restrict__ pred4,   // 2 float4 per group of 4 rows
    const float4* __restrict__ tgt4,
    const float4* __restrict__ prev4,
    const int4*   __restrict__ pv4,
    const float*  __restrict__ pred,    // scalar tail
    const float*  __restrict__ tgt,
    const float*  __restrict__ prev,
    const int*    __restrict__ pv,
    float* __restrict__ out,            // zeroed per call; one atomicAdd/block
    long long n, long long nthreads, float inv_n)
{
    const long long ngroups = n >> 2;
    const long long tid = (long long)blockIdx.x * BLOCK + threadIdx.x;
    const long long stride = nthreads;

    float sc = 0.f, sw = 0.f, sv = 0.f, sd = 0.f;

    for (long long g = tid; g < ngroups; g += stride) {
        const float4 p0 = pred4[2 * g];
        const float4 p1 = pred4[2 * g + 1];
        const float4 t  = tgt4[g];
        const float4 pr = prev4[g];
        const int4   v  = pv4[g];

        const float l[4]  = { p0.x, p0.z, p1.x, p1.z };
        const float u[4]  = { p0.y, p0.w, p1.y, p1.w };
        const float tt[4] = { t.x, t.y, t.z, t.w };
        const float pp[4] = { pr.x, pr.y, pr.z, pr.w };
        const int   vv[4] = { v.x, v.y, v.z, v.w };

        #pragma unroll
        for (int j = 0; j < 4; ++j) {
            const float c = (l[j] + u[j]) * 0.5f;
            const float d = tt[j] - c;
            sc += d * d;
            sw += u[j] - l[j];
            sv += fmaxf(l[j] - u[j], 0.f);
            const float dif = (vv[j] == 0) ? (c - pp[j]) : (pp[j] - c);
            sd += fmaxf(dif, 0.f);
        }
    }
    // Scalar tail (n % 4 leftovers).
    for (long long i = (ngroups << 2) + tid; i < n; i += stride) {
        const float lo = pred[2 * i];
        const float up = pred[2 * i + 1];
        const float c  = (lo + up) * 0.5f;
        const float d  = tgt[i] - c;
        sc += d * d;
        sw += up - lo;
        sv += fmaxf(lo - up, 0.f);
        const float dif = (pv[i] == 0) ? (c - prev[i]) : (prev[i] - c);
        sd += fmaxf(dif, 0.f);
    }

    block_reduce4(sc, sw, sv, sd);

    if (threadIdx.x == 0) {
        const float contrib = (10.0f * sc + 0.1f * sw + 10.0f * sv + 0.5f * sd) * inv_n;
        // Native global_atomic_add_f32 at the LLC, relaxed — no L2 flush.
        unsafeAtomicAdd(out, contrib);
    }
}

extern "C" void kernel_launch(void* const* d_in, const int* in_sizes, int n_in,
                              void* d_out, int out_size, void* d_ws, size_t ws_size,
                              hipStream_t stream) {
    const float* pred = (const float*)d_in[0];   // (N,2) f32
    const float* tgt  = (const float*)d_in[1];   // (N,1) f32
    const float* prev = (const float*)d_in[2];   // (N,)  f32
    const int*   pv   = (const int*)d_in[3];     // (N,)  int (0/1)
    float*       out  = (float*)d_out;

    const long long n = (long long)in_sizes[2];  // prev_pci element count = N

    hipMemsetAsync(out, 0, sizeof(float), stream);

    loss_fused<<<GRID_MAX, BLOCK, 0, stream>>>(
        (const float4*)pred, (const float4*)tgt, (const float4*)prev, (const int4*)pv,
        pred, tgt, prev, pv,
        out, n, (long long)GRID_MAX * BLOCK, 1.0f / (float)n);
}

// Round 5
// 47.039 us; speedup vs baseline: 3.3415x; 1.0192x over previous
//
#include <hip/hip_runtime.h>

// CustomLoss: fused 4-way reduction over N rows -> scalar loss.
// total = 10*mean((t-c)^2) + 0.1*mean(u-l) + 10*mean(max(l-u,0)) + 0.5*sum(dir)/N
// where c=(l+u)/2, dir = pv==0 ? relu(c-prev) : relu(prev-c).
//
// Round 5: round-1 main loop (VGPR ~20-24, 8 blocks/CU — proven best) +
// relaxed device-scope fp32 atomicAdd per block into d_out[0].
// d_out[0] is zeroed by a TINY INIT KERNEL on the same compute queue.
//
// Lessons encoded:
//  - R3: agent-scope fences / ACQ_REL RMWs => per-XCD L2 writeback+inv
//    (non-coherent L2s) => ~200us for 2048 blocks. Use RELAXED atomics only.
//  - R4: hipMemsetAsync node in the graph => SDMA/blit cross-queue sync,
//    ~14us per replay. Zero with a compute kernel instead.
//  - R2: unroll-4 crosses the VGPR=64 occupancy cliff; BW is the limit
//    (~6 TB/s vector-memory path), not latency — keep the simple loop.

constexpr int BLOCK = 256;
constexpr int GRID_MAX = 2048;

__device__ inline void block_reduce4(float& a, float& b, float& c, float& d) {
    #pragma unroll
    for (int off = 32; off > 0; off >>= 1) {
        a += __shfl_down(a, off);
        b += __shfl_down(b, off);
        c += __shfl_down(c, off);
        d += __shfl_down(d, off);
    }
    __shared__ float s[4][BLOCK / 64];
    const int lane = threadIdx.x & 63;
    const int wid  = threadIdx.x >> 6;
    if (lane == 0) { s[0][wid] = a; s[1][wid] = b; s[2][wid] = c; s[3][wid] = d; }
    __syncthreads();
    if (threadIdx.x == 0) {
        #pragma unroll
        for (int w = 1; w < BLOCK / 64; ++w) {
            a += s[0][w]; b += s[1][w]; c += s[2][w]; d += s[3][w];
        }
    }
}

__global__ void init_out(float* __restrict__ out) {
    if (threadIdx.x == 0) out[0] = 0.0f;
}

__global__ __launch_bounds__(BLOCK) void loss_fused(
    const float4* __restrict__ pred4,   // 2 float4 per group of 4 rows
    const float4* __restrict__ tgt4,
    const float4* __restrict__ prev4,
    const int4*   __restrict__ pv4,
    const float*  __restrict__ pred,    // scalar tail
    const float*  __restrict__ tgt,
    const float*  __restrict__ prev,
    const int*    __restrict__ pv,
    float* __restrict__ out,            // zeroed by init_out; one atomicAdd/block
    long long n, long long nthreads, float inv_n)
{
    const long long ngroups = n >> 2;
    const long long tid = (long long)blockIdx.x * BLOCK + threadIdx.x;
    const long long stride = nthreads;

    float sc = 0.f, sw = 0.f, sv = 0.f, sd = 0.f;

    for (long long g = tid; g < ngroups; g += stride) {
        const float4 p0 = pred4[2 * g];
        const float4 p1 = pred4[2 * g + 1];
        const float4 t  = tgt4[g];
        const float4 pr = prev4[g];
        const int4   v  = pv4[g];

        const float l[4]  = { p0.x, p0.z, p1.x, p1.z };
        const float u[4]  = { p0.y, p0.w, p1.y, p1.w };
        const float tt[4] = { t.x, t.y, t.z, t.w };
        const float pp[4] = { pr.x, pr.y, pr.z, pr.w };
        const int   vv[4] = { v.x, v.y, v.z, v.w };

        #pragma unroll
        for (int j = 0; j < 4; ++j) {
            const float c = (l[j] + u[j]) * 0.5f;
            const float d = tt[j] - c;
            sc += d * d;
            sw += u[j] - l[j];
            sv += fmaxf(l[j] - u[j], 0.f);
            const float dif = (vv[j] == 0) ? (c - pp[j]) : (pp[j] - c);
            sd += fmaxf(dif, 0.f);
        }
    }
    // Scalar tail (n % 4 leftovers).
    for (long long i = (ngroups << 2) + tid; i < n; i += stride) {
        const float lo = pred[2 * i];
        const float up = pred[2 * i + 1];
        const float c  = (lo + up) * 0.5f;
        const float d  = tgt[i] - c;
        sc += d * d;
        sw += up - lo;
        sv += fmaxf(lo - up, 0.f);
        const float dif = (pv[i] == 0) ? (c - prev[i]) : (prev[i] - c);
        sd += fmaxf(dif, 0.f);
    }

    block_reduce4(sc, sw, sv, sd);

    if (threadIdx.x == 0) {
        const float contrib = (10.0f * sc + 0.1f * sw + 10.0f * sv + 0.5f * sd) * inv_n;
        // Relaxed device-scope atomic: executes at the LLC, no cache
        // maintenance, no fences. (ACQ_REL here was the round-3 disaster.)
        __hip_atomic_fetch_add(out, contrib, __ATOMIC_RELAXED, __HIP_MEMORY_SCOPE_AGENT);
    }
}

extern "C" void kernel_launch(void* const* d_in, const int* in_sizes, int n_in,
                              void* d_out, int out_size, void* d_ws, size_t ws_size,
                              hipStream_t stream) {
    const float* pred = (const float*)d_in[0];   // (N,2) f32
    const float* tgt  = (const float*)d_in[1];   // (N,1) f32
    const float* prev = (const float*)d_in[2];   // (N,)  f32
    const int*   pv   = (const int*)d_in[3];     // (N,)  int (0/1)
    float*       out  = (float*)d_out;

    const long long n = (long long)in_sizes[2];  // prev_pci element count = N

    init_out<<<1, 64, 0, stream>>>(out);

    loss_fused<<<GRID_MAX, BLOCK, 0, stream>>>(
        (const float4*)pred, (const float4*)tgt, (const float4*)prev, (const int4*)pv,
        pred, tgt, prev, pv,
        out, n, (long long)GRID_MAX * BLOCK, 1.0f / (float)n);
}

// Round 6
// 33.384 us; speedup vs baseline: 4.7083x; 1.4090x over previous
//
#include <hip/hip_runtime.h>

// CustomLoss: fused 4-way reduction over N rows -> scalar loss.
// total = 10*mean((t-c)^2) + 0.1*mean(u-l) + 10*mean(max(l-u,0)) + 0.5*sum(dir)/N
// where c=(l+u)/2, dir = pv==0 ? relu(c-prev) : relu(prev-c).
//
// Round 6: back to the round-1 two-kernel structure (33.7 us, best so far),
// grid 2048 -> 1024 (exactly 8 uniform iters/thread; finalize reads 16 KB).
//
// Lessons encoded (do not reintroduce):
//  - R3: agent-scope fences / ACQ_REL RMWs => per-XCD L2 writeback+inv
//    (~200us for 2048 blocks). Never fence per-block on gfx950.
//  - R4/R5: 2048 same-line atomic RMWs serialize at the LLC (~6-7ns each)
//    => ~13us burst tail. Partials-array + tiny finalize kernel is cheaper.
//  - R2: unroll-4 crossed the VGPR=64 occupancy cliff and anyway the loop
//    is BW-bound at ~5.9 TB/s (92-94% of the 6.29 TB/s streaming ceiling);
//    more MLP / occupancy changes move nothing.

constexpr int BLOCK = 256;
constexpr int GRID_MAX = 1024;

__device__ inline void block_reduce4(float& a, float& b, float& c, float& d) {
    #pragma unroll
    for (int off = 32; off > 0; off >>= 1) {
        a += __shfl_down(a, off);
        b += __shfl_down(b, off);
        c += __shfl_down(c, off);
        d += __shfl_down(d, off);
    }
    __shared__ float s[4][BLOCK / 64];
    const int lane = threadIdx.x & 63;
    const int wid  = threadIdx.x >> 6;
    if (lane == 0) { s[0][wid] = a; s[1][wid] = b; s[2][wid] = c; s[3][wid] = d; }
    __syncthreads();
    if (threadIdx.x == 0) {
        #pragma unroll
        for (int w = 1; w < BLOCK / 64; ++w) {
            a += s[0][w]; b += s[1][w]; c += s[2][w]; d += s[3][w];
        }
    }
}

__global__ __launch_bounds__(BLOCK) void loss_partial(
    const float4* __restrict__ pred4,   // 2 float4 per group of 4 rows
    const float4* __restrict__ tgt4,
    const float4* __restrict__ prev4,
    const int4*   __restrict__ pv4,
    const float*  __restrict__ pred,    // scalar tail
    const float*  __restrict__ tgt,
    const float*  __restrict__ prev,
    const int*    __restrict__ pv,
    float4* __restrict__ partials,
    long long n, long long nthreads)
{
    const long long ngroups = n >> 2;
    const long long tid = (long long)blockIdx.x * BLOCK + threadIdx.x;
    const long long stride = nthreads;

    float sc = 0.f, sw = 0.f, sv = 0.f, sd = 0.f;

    for (long long g = tid; g < ngroups; g += stride) {
        const float4 p0 = pred4[2 * g];
        const float4 p1 = pred4[2 * g + 1];
        const float4 t  = tgt4[g];
        const float4 pr = prev4[g];
        const int4   v  = pv4[g];

        const float l[4]  = { p0.x, p0.z, p1.x, p1.z };
        const float u[4]  = { p0.y, p0.w, p1.y, p1.w };
        const float tt[4] = { t.x, t.y, t.z, t.w };
        const float pp[4] = { pr.x, pr.y, pr.z, pr.w };
        const int   vv[4] = { v.x, v.y, v.z, v.w };

        #pragma unroll
        for (int j = 0; j < 4; ++j) {
            const float c = (l[j] + u[j]) * 0.5f;
            const float d = tt[j] - c;
            sc += d * d;
            sw += u[j] - l[j];
            sv += fmaxf(l[j] - u[j], 0.f);
            const float dif = (vv[j] == 0) ? (c - pp[j]) : (pp[j] - c);
            sd += fmaxf(dif, 0.f);
        }
    }
    // Scalar tail (n % 4 leftovers).
    for (long long i = (ngroups << 2) + tid; i < n; i += stride) {
        const float lo = pred[2 * i];
        const float up = pred[2 * i + 1];
        const float c  = (lo + up) * 0.5f;
        const float d  = tgt[i] - c;
        sc += d * d;
        sw += up - lo;
        sv += fmaxf(lo - up, 0.f);
        const float dif = (pv[i] == 0) ? (c - prev[i]) : (prev[i] - c);
        sd += fmaxf(dif, 0.f);
    }

    block_reduce4(sc, sw, sv, sd);
    if (threadIdx.x == 0) {
        partials[blockIdx.x] = make_float4(sc, sw, sv, sd);
    }
}

__global__ __launch_bounds__(BLOCK) void loss_final(
    const float4* __restrict__ partials, int nparts,
    float* __restrict__ out, float inv_n)
{
    float sc = 0.f, sw = 0.f, sv = 0.f, sd = 0.f;
    for (int i = threadIdx.x; i < nparts; i += BLOCK) {
        const float4 p = partials[i];
        sc += p.x; sw += p.y; sv += p.z; sd += p.w;
    }
    block_reduce4(sc, sw, sv, sd);
    if (threadIdx.x == 0) {
        out[0] = 10.0f * sc * inv_n
               + 0.1f  * sw * inv_n
               + 10.0f * sv * inv_n
               + 0.5f  * sd * inv_n;
    }
}

extern "C" void kernel_launch(void* const* d_in, const int* in_sizes, int n_in,
                              void* d_out, int out_size, void* d_ws, size_t ws_size,
                              hipStream_t stream) {
    const float* pred = (const float*)d_in[0];   // (N,2) f32
    const float* tgt  = (const float*)d_in[1];   // (N,1) f32
    const float* prev = (const float*)d_in[2];   // (N,)  f32
    const int*   pv   = (const int*)d_in[3];     // (N,)  int (0/1)
    float*       out  = (float*)d_out;

    const long long n = (long long)in_sizes[2];  // prev_pci element count = N

    int grid = GRID_MAX;
    while (grid > 1 && ws_size < (size_t)grid * sizeof(float4)) {
        grid >>= 1;
    }
    float4* partials = (float4*)d_ws;

    loss_partial<<<grid, BLOCK, 0, stream>>>(
        (const float4*)pred, (const float4*)tgt, (const float4*)prev, (const int4*)pv,
        pred, tgt, prev, pv,
        partials, n, (long long)grid * BLOCK);

    loss_final<<<1, BLOCK, 0, stream>>>(partials, grid, out, 1.0f / (float)n);
}